// Round 5
// baseline (1007.218 us; speedup 1.0000x reference)
//
#include <hip/hip_runtime.h>
#include <math.h>

#define H        2048
#define HD       12288      // (NG+1)*H
#define DICT     50000
#define FDIM     6
#define RDIM     1
#define IN_DIM   16
#define EPS_F    1e-8f

// d_out flat offsets (floats), in reference return order
#define OFF_PI   ((size_t)0)
#define OFF_V    ((size_t)8)
#define OFF_H    ((size_t)9)
#define OFF_C    ((size_t)2057)
#define OFF_FK   ((size_t)4105)
#define OFF_FV   ((size_t)304105)   // ≡ 1 (mod 4): float j with j≡3 (mod 4) is 16B-aligned
#define OFF_RK   ((size_t)102704105)
#define OFF_RV   ((size_t)102754105) // ≡ 1 (mod 4), same shift

// megakernel block ranges
#define R_CHUNK      125                 // vals rows per block
#define NBLK_DICT    (DICT / R_CHUNK)    // 400
#define NBLK_VALS    (2 * NBLK_DICT)     // 800
#define NBLK_PREACT  (HD / 8)            // 1536 (8 rows per 512-thread block)
#define NBLK_TOTAL   (NBLK_VALS + NBLK_PREACT)

typedef float f4v __attribute__((ext_vector_type(4)));   // true vector type: NT-builtin-compatible

__device__ __forceinline__ float sigf(float v) { return 1.0f / (1.0f + expf(-v)); }

// ---------------- zero scratch accumulators ----------------
__global__ void k_zero(float* __restrict__ p, int n) {
    int i = blockIdx.x * 256 + threadIdx.x;
    if (i < n) p[i] = 0.0f;
}

// ---------------- megakernel: vals copy+wsum+sims (blocks 0..799) | preact (800..2335) ----
__global__ __launch_bounds__(512) void k_mega(
    const float* __restrict__ f_keys, const float* __restrict__ r_keys,
    const float* __restrict__ f_vals, const float* __restrict__ r_vals,
    const float* __restrict__ x,
    const float* __restrict__ W_h2h, const float* __restrict__ W_i2h,
    const float* __restrict__ b_h2h, const float* __restrict__ b_i2h,
    const float* __restrict__ h,
    float* __restrict__ out_fv, float* __restrict__ out_rv,
    float* __restrict__ out_fk, float* __restrict__ out_rk,
    float* __restrict__ memfun, float* __restrict__ memrul,
    float* __restrict__ sums, float* __restrict__ preact)
{
    const int b   = blockIdx.x;
    const int tid = threadIdx.x;

    if (b >= NBLK_VALS) {
        // ---- preact: wave per row, 8 rows per block ----
        const int row  = (b - NBLK_VALS) * 8 + (tid >> 6);
        const int lane = tid & 63;
        const float4* Wv = (const float4*)(W_h2h + (size_t)row * H);
        const float4* hv = (const float4*)h;
        float acc = 0.0f;
#pragma unroll
        for (int k = 0; k < 8; ++k) {
            float4 w4 = Wv[lane + (k << 6)];
            float4 h4 = hv[lane + (k << 6)];
            acc += w4.x * h4.x + w4.y * h4.y + w4.z * h4.z + w4.w * h4.w;
        }
        if (lane < IN_DIM) acc += W_i2h[(size_t)row * IN_DIM + lane] * x[lane];
#pragma unroll
        for (int off = 32; off > 0; off >>= 1) acc += __shfl_down(acc, off);
        if (lane == 0) preact[row] = acc + b_h2h[row] + b_i2h[row];
        return;
    }

    // ---- vals blocks: one full-width row (512 float4) per iteration ----
    __shared__ float wl[R_CHUNK];
    const int  dict = (b >= NBLK_DICT) ? 1 : 0;
    const int  row0 = (dict ? b - NBLK_DICT : b) * R_CHUNK;

    const float* vals = dict ? r_vals : f_vals;
    float*       outv = dict ? out_rv : out_fv;   // base ≡ 1 (mod 4 floats)
    float*       mem  = dict ? memrul : memfun;

    // fused keys output copy
    if (!dict) {
        for (int i = tid; i < R_CHUNK * FDIM; i += 512)
            out_fk[(size_t)row0 * FDIM + i] = f_keys[(size_t)row0 * FDIM + i];
    } else if (tid < R_CHUNK) {
        out_rk[row0 + tid] = r_keys[row0 + tid];
    }

    // fused exp-sims for this block's rows (softmax max-shift unneeded: |sim|<=1)
    if (tid < R_CHUNK) {
        const int row = row0 + tid;
        float e;
        if (!dict) {
            float qn[FDIM]; float qs = 0.0f;
#pragma unroll
            for (int d = 0; d < FDIM; ++d) { float q = x[d]; qn[d] = q; qs += q * q; }
            const float qi = 1.0f / (sqrtf(qs) + EPS_F);
            float ks = 0.0f, dot = 0.0f;
#pragma unroll
            for (int d = 0; d < FDIM; ++d) {
                float kv = f_keys[(size_t)row * FDIM + d];
                ks += kv * kv; dot += kv * qn[d];
            }
            e = expf((dot * qi) / (sqrtf(ks) + EPS_F));
        } else {
            float q  = x[FDIM];
            float kv = r_keys[row];
            e = expf((kv * (q / (fabsf(q) + EPS_F))) / (fabsf(kv) + EPS_F));
        }
        wl[tid] = e;
    }
    __syncthreads();
    if (tid == 0) {
        float s = 0.0f;
        for (int i = 0; i < R_CHUNK; ++i) s += wl[i];
        atomicAdd(&sums[dict], s);
    }

    // streaming copy + weighted sum.
    // Loads: aligned float4 (thread t owns input columns 4t..4t+3).
    // Stores: 16B-ALIGNED float4 at +3-float shift: out float4 j=4t+3 needs
    // (v[t].w, v[t+1].x, v[t+1].y, v[t+1].z) — neighbor via __shfl_down;
    // lane 63 fetches its neighbor float4 directly. Row edges scalar.
    const f4v* vv = (const f4v*)vals;
    const int lane = tid & 63;
    float a0 = 0.f, a1 = 0.f, a2 = 0.f, a3 = 0.f;
#pragma unroll 4
    for (int i = 0; i < R_CHUNK; ++i) {
        const size_t idx = (size_t)(row0 + i) * 512 + tid;
        f4v v = __builtin_nontemporal_load(&vv[idx]);
        const float w = wl[i];
        a0 += w * v.x; a1 += w * v.y; a2 += w * v.z; a3 += w * v.w;

        float nx = __shfl_down(v.x, 1);
        float ny = __shfl_down(v.y, 1);
        float nz = __shfl_down(v.z, 1);
        if (lane == 63 && tid != 511) {
            f4v e = vv[idx + 1];               // cross-wave neighbor (regular load)
            nx = e.x; ny = e.y; nz = e.z;
        }
        float* orow = outv + (size_t)(row0 + i) * 2048;
        if (tid < 511) {
            f4v s; s.x = v.w; s.y = nx; s.z = ny; s.w = nz;
            __builtin_nontemporal_store(s, (f4v*)(orow + 3) + tid);
        } else {
            __builtin_nontemporal_store(v.w, orow + 2047);
        }
        if (tid == 0) {
            __builtin_nontemporal_store(v.x, orow + 0);
            __builtin_nontemporal_store(v.y, orow + 1);
            __builtin_nontemporal_store(v.z, orow + 2);
        }
    }
    const int c = tid * 4;
    atomicAdd(&mem[c + 0], a0);
    atomicAdd(&mem[c + 1], a1);
    atomicAdd(&mem[c + 2], a2);
    atomicAdd(&mem[c + 3], a3);
}

// ---------------- gates -> c_t, h_t; write h/c outputs + write_idx rows ----------------
__global__ __launch_bounds__(256) void k_combine(
    const float* __restrict__ preact, const float* __restrict__ c_in,
    const float* __restrict__ memfun, const float* __restrict__ memrul,
    const float* __restrict__ sums,
    const float* __restrict__ x, const int* __restrict__ widx_p,
    float* __restrict__ out, float* __restrict__ ht_ws)
{
    const int j = blockIdx.x * 256 + threadIdx.x;
    if (j >= H) return;
    const int widx = *widx_p;
    const float invf = 1.0f / sums[0];
    const float invr = 1.0f / sums[1];

    float f_t   = sigf(preact[0 * H + j]);
    float i_t   = sigf(preact[1 * H + j]);
    float o_t   = sigf(preact[2 * H + j]);
    float fun_t = sigf(preact[3 * H + j]);
    float rul_t = sigf(preact[4 * H + j]);
    float c_new = tanhf(preact[5 * H + j]);

    float ct = f_t * c_in[j] + i_t * c_new
             + fun_t * tanhf(memfun[j] * invf) + rul_t * tanhf(memrul[j] * invr);
    float ht = o_t * tanhf(ct);

    out[OFF_H + j] = ht;
    out[OFF_C + j] = ct;
    ht_ws[j] = ht;

    out[OFF_FV + (size_t)widx * H + j] = (j < H / 2) ? ct : 0.0f;
    out[OFF_RV + (size_t)widx * H + j] = (j < H / 2) ? 0.0f : ct;
    if (j < FDIM)  out[OFF_FK + (size_t)widx * FDIM + j] = x[j];
    if (j == FDIM) out[OFF_RK + (size_t)widx] = x[FDIM];
}

// ---------------- ha = relu(W_ih @ h_t + b_ih)  (wave per row) ----------------
__global__ __launch_bounds__(256) void k_hidden(
    const float* __restrict__ W_ih, const float* __restrict__ b_ih,
    const float* __restrict__ ht, float* __restrict__ ha)
{
    int gid  = blockIdx.x * blockDim.x + threadIdx.x;
    int row  = gid >> 6;
    int lane = threadIdx.x & 63;
    if (row >= H) return;
    const float4* Wv = (const float4*)(W_ih + (size_t)row * H);
    const float4* hv = (const float4*)ht;
    float acc = 0.0f;
#pragma unroll
    for (int k = 0; k < 8; ++k) {
        float4 w4 = Wv[lane + (k << 6)];
        float4 h4 = hv[lane + (k << 6)];
        acc += w4.x * h4.x + w4.y * h4.y + w4.z * h4.z + w4.w * h4.w;
    }
#pragma unroll
    for (int off = 32; off > 0; off >>= 1) acc += __shfl_down(acc, off);
    if (lane == 0) ha[row] = fmaxf(acc + b_ih[row], 0.0f);
}

// ---------------- heads stage 1: 9 parallel logit GEMVs ----------------
__global__ __launch_bounds__(256) void k_heads1(
    const float* __restrict__ W_actor, const float* __restrict__ b_actor,
    const float* __restrict__ W_critic, const float* __restrict__ b_critic,
    const float* __restrict__ ha, float* __restrict__ logits)
{
    __shared__ float red[4];
    const int o   = blockIdx.x;           // 0..8
    const int tid = threadIdx.x;
    const float* row = (o < 8) ? (W_actor + (size_t)o * H) : W_critic;
    const float4* rv = (const float4*)row;
    const float4* hv = (const float4*)ha;
    float acc = 0.0f;
#pragma unroll
    for (int k = 0; k < 2; ++k) {
        int idx = tid + (k << 8);
        float4 w4 = rv[idx];
        float4 h4 = hv[idx];
        acc += w4.x * h4.x + w4.y * h4.y + w4.z * h4.z + w4.w * h4.w;
    }
#pragma unroll
    for (int off = 32; off > 0; off >>= 1) acc += __shfl_down(acc, off);
    if ((tid & 63) == 0) red[tid >> 6] = acc;
    __syncthreads();
    if (tid == 0)
        logits[o] = red[0] + red[1] + red[2] + red[3] + ((o < 8) ? b_actor[o] : b_critic[0]);
}

// ---------------- heads stage 2: softmax over 8 + critic ----------------
__global__ __launch_bounds__(64) void k_heads2(
    const float* __restrict__ logits, float* __restrict__ out)
{
    if (threadIdx.x == 0) {
        float m = logits[0];
        for (int o = 1; o < 8; ++o) m = fmaxf(m, logits[o]);
        float e[8], s = 0.0f;
        for (int o = 0; o < 8; ++o) { e[o] = expf(logits[o] - m); s += e[o]; }
        for (int o = 0; o < 8; ++o) out[OFF_PI + o] = e[o] / s;
        out[OFF_V] = logits[8];
    }
}

extern "C" void kernel_launch(void* const* d_in, const int* in_sizes, int n_in,
                              void* d_out, int out_size, void* d_ws, size_t ws_size,
                              hipStream_t stream)
{
    const float* x        = (const float*)d_in[0];
    const float* h        = (const float*)d_in[1];
    const float* c        = (const float*)d_in[2];
    const float* W_i2h    = (const float*)d_in[3];
    const float* b_i2h    = (const float*)d_in[4];
    const float* W_h2h    = (const float*)d_in[5];
    const float* b_h2h    = (const float*)d_in[6];
    const float* f_keys   = (const float*)d_in[7];
    const float* f_vals   = (const float*)d_in[8];
    const float* r_keys   = (const float*)d_in[9];
    const float* r_vals   = (const float*)d_in[10];
    const float* W_ih     = (const float*)d_in[11];
    const float* b_ih     = (const float*)d_in[12];
    const float* W_actor  = (const float*)d_in[13];
    const float* b_actor  = (const float*)d_in[14];
    const float* W_critic = (const float*)d_in[15];
    const float* b_critic = (const float*)d_in[16];
    const int*   widx     = (const int*)d_in[17];

    float* out = (float*)d_out;
    float* ws  = (float*)d_ws;

    // ws layout (floats)
    float* preact = ws;                 // 12288
    float* memfun = ws + 12288;         // 2048 ┐
    float* memrul = ws + 14336;         // 2048 ├ zeroed together (4098 floats)
    float* sums   = ws + 16384;         // 2    ┘
    float* ht_ws  = ws + 16388;         // 2048 (16B-aligned)
    float* ha     = ws + 18436;         // 2048 (16B-aligned)
    float* logits = ws + 20484;         // 9

    // 1. zero accumulators (ws is poisoned; atomics accumulate into these)
    k_zero<<<17, 256, 0, stream>>>(memfun, 2 * H + 2);

    // 2. megakernel: vals copy+wsum+sims+keys (blocks 0..799) | preact (800..2335)
    k_mega<<<NBLK_TOTAL, 512, 0, stream>>>(
        f_keys, r_keys, f_vals, r_vals, x,
        W_h2h, W_i2h, b_h2h, b_i2h, h,
        out + OFF_FV, out + OFF_RV, out + OFF_FK, out + OFF_RK,
        memfun, memrul, sums, preact);

    // 3. gates -> c_t, h_t (applies 1/sum normalization); h/c outputs + write_idx rows
    k_combine<<<H / 256, 256, 0, stream>>>(preact, c, memfun, memrul, sums, x, widx, out, ht_ws);

    // 4. heads
    k_hidden<<<H / 4, 256, 0, stream>>>(W_ih, b_ih, ht_ws, ha);
    k_heads1<<<9, 256, 0, stream>>>(W_actor, b_actor, W_critic, b_critic, ha, logits);
    k_heads2<<<1, 64, 0, stream>>>(logits, out);
}

// Round 6
// 475.638 us; speedup vs baseline: 2.1176x; 2.1176x over previous
//
#include <hip/hip_runtime.h>
#include <math.h>

#define H        2048
#define HD       12288      // (NG+1)*H
#define DICT     50000
#define FDIM     6
#define RDIM     1
#define IN_DIM   16
#define EPS_F    1e-8f

// d_out flat offsets (floats), in reference return order
#define OFF_PI   ((size_t)0)
#define OFF_V    ((size_t)8)
#define OFF_H    ((size_t)9)
#define OFF_C    ((size_t)2057)
#define OFF_FK   ((size_t)4105)
#define OFF_FV   ((size_t)304105)    // ≡ 1 (mod 4): row-local float j≡3 (mod 4) is 16B-aligned
#define OFF_RK   ((size_t)102704105)
#define OFF_RV   ((size_t)102754105) // ≡ 1 (mod 4), same phase

// megakernel block ranges
#define R_CHUNK      125                 // vals rows per block
#define NBLK_DICT    (DICT / R_CHUNK)    // 400
#define NBLK_VALS    (2 * NBLK_DICT)     // 800
#define NBLK_PREACT  (HD / 8)            // 1536 (8 rows per 512-thread block)
#define NBLK_TOTAL   (NBLK_VALS + NBLK_PREACT)

typedef float f4v __attribute__((ext_vector_type(4)));

__device__ __forceinline__ float sigf(float v) { return 1.0f / (1.0f + expf(-v)); }

// ---------------- zero scratch accumulators ----------------
__global__ void k_zero(float* __restrict__ p, int n) {
    int i = blockIdx.x * 256 + threadIdx.x;
    if (i < n) p[i] = 0.0f;
}

// ---------------- megakernel: vals copy+wsum+sims (blocks 0..799) | preact (800..2335) ----
__global__ __launch_bounds__(512) void k_mega(
    const float* __restrict__ f_keys, const float* __restrict__ r_keys,
    const float* __restrict__ f_vals, const float* __restrict__ r_vals,
    const float* __restrict__ x,
    const float* __restrict__ W_h2h, const float* __restrict__ W_i2h,
    const float* __restrict__ b_h2h, const float* __restrict__ b_i2h,
    const float* __restrict__ h,
    float* __restrict__ out_fv, float* __restrict__ out_rv,
    float* __restrict__ out_fk, float* __restrict__ out_rk,
    float* __restrict__ memfun, float* __restrict__ memrul,
    float* __restrict__ sums, float* __restrict__ preact)
{
    const int b   = blockIdx.x;
    const int tid = threadIdx.x;

    if (b >= NBLK_VALS) {
        // ---- preact: wave per row, 8 rows per block ----
        const int row  = (b - NBLK_VALS) * 8 + (tid >> 6);
        const int lane = tid & 63;
        const float4* Wv = (const float4*)(W_h2h + (size_t)row * H);
        const float4* hv = (const float4*)h;
        float acc = 0.0f;
#pragma unroll
        for (int k = 0; k < 8; ++k) {
            float4 w4 = Wv[lane + (k << 6)];
            float4 h4 = hv[lane + (k << 6)];
            acc += w4.x * h4.x + w4.y * h4.y + w4.z * h4.z + w4.w * h4.w;
        }
        if (lane < IN_DIM) acc += W_i2h[(size_t)row * IN_DIM + lane] * x[lane];
#pragma unroll
        for (int off = 32; off > 0; off >>= 1) acc += __shfl_down(acc, off);
        if (lane == 0) preact[row] = acc + b_h2h[row] + b_i2h[row];
        return;
    }

    // ---- vals blocks ----
    __shared__ float wl[R_CHUNK];
    const int  dict = (b >= NBLK_DICT) ? 1 : 0;
    const int  row0 = (dict ? b - NBLK_DICT : b) * R_CHUNK;

    const float* vals = dict ? r_vals : f_vals;
    float*       outv = dict ? out_rv : out_fv;   // base ≡ 1 (mod 4 floats)
    float*       mem  = dict ? memrul : memfun;

    // fused keys output copy
    if (!dict) {
        for (int i = tid; i < R_CHUNK * FDIM; i += 512)
            out_fk[(size_t)row0 * FDIM + i] = f_keys[(size_t)row0 * FDIM + i];
    } else if (tid < R_CHUNK) {
        out_rk[row0 + tid] = r_keys[row0 + tid];
    }

    // fused exp-sims for this block's rows (softmax max-shift unneeded: |sim|<=1)
    if (tid < R_CHUNK) {
        const int row = row0 + tid;
        float e;
        if (!dict) {
            float qn[FDIM]; float qs = 0.0f;
#pragma unroll
            for (int d = 0; d < FDIM; ++d) { float q = x[d]; qn[d] = q; qs += q * q; }
            const float qi = 1.0f / (sqrtf(qs) + EPS_F);
            float ks = 0.0f, dot = 0.0f;
#pragma unroll
            for (int d = 0; d < FDIM; ++d) {
                float kv = f_keys[(size_t)row * FDIM + d];
                ks += kv * kv; dot += kv * qn[d];
            }
            e = expf((dot * qi) / (sqrtf(ks) + EPS_F));
        } else {
            float q  = x[FDIM];
            float kv = r_keys[row];
            e = expf((kv * (q / (fabsf(q) + EPS_F))) / (fabsf(kv) + EPS_F));
        }
        wl[tid] = e;
    }
    __syncthreads();
    if (tid == 0) {
        float s = 0.0f;
        for (int i = 0; i < R_CHUNK; ++i) s += wl[i];
        atomicAdd(&sums[dict], s);
    }

    // streaming copy + weighted sum, SHIFTED-QUAD ownership:
    // thread t<511 owns row-local columns j0..j0+3, j0 = 4t+3  (16B-aligned in out).
    // Loads: 4 scalar cached loads (4B-aligned; L1 absorbs line overlap).
    // Store: ONE aligned cached dwordx4 -> wave writes 1KB contiguous, L2 combines.
    // Thread 511 owns edge columns {0,1,2,2047}.
    const float* vrow0 = vals + (size_t)row0 * 2048;
    float*       orow0 = outv + (size_t)row0 * 2048;
    float a0 = 0.f, a1 = 0.f, a2 = 0.f, a3 = 0.f;

    if (tid < 511) {
        const int j0 = 4 * tid + 3;
#pragma unroll 5
        for (int i = 0; i < R_CHUNK; ++i) {
            const float* vr = vrow0 + (size_t)i * 2048 + j0;
            float v0 = vr[0], v1 = vr[1], v2 = vr[2], v3 = vr[3];
            const float w = wl[i];
            a0 += w * v0; a1 += w * v1; a2 += w * v2; a3 += w * v3;
            f4v s; s.x = v0; s.y = v1; s.z = v2; s.w = v3;
            *(f4v*)(orow0 + (size_t)i * 2048 + j0) = s;
        }
        atomicAdd(&mem[j0 + 0], a0);
        atomicAdd(&mem[j0 + 1], a1);
        atomicAdd(&mem[j0 + 2], a2);
        atomicAdd(&mem[j0 + 3], a3);
    } else {
#pragma unroll 5
        for (int i = 0; i < R_CHUNK; ++i) {
            const float* vr = vrow0 + (size_t)i * 2048;
            float*       orow = orow0 + (size_t)i * 2048;
            float v0 = vr[0], v1 = vr[1], v2 = vr[2], v3 = vr[2047];
            const float w = wl[i];
            a0 += w * v0; a1 += w * v1; a2 += w * v2; a3 += w * v3;
            orow[0] = v0; orow[1] = v1; orow[2] = v2; orow[2047] = v3;
        }
        atomicAdd(&mem[0],    a0);
        atomicAdd(&mem[1],    a1);
        atomicAdd(&mem[2],    a2);
        atomicAdd(&mem[2047], a3);
    }
}

// ---------------- gates -> c_t, h_t; write h/c outputs + write_idx rows ----------------
__global__ __launch_bounds__(256) void k_combine(
    const float* __restrict__ preact, const float* __restrict__ c_in,
    const float* __restrict__ memfun, const float* __restrict__ memrul,
    const float* __restrict__ sums,
    const float* __restrict__ x, const int* __restrict__ widx_p,
    float* __restrict__ out, float* __restrict__ ht_ws)
{
    const int j = blockIdx.x * 256 + threadIdx.x;
    if (j >= H) return;
    const int widx = *widx_p;
    const float invf = 1.0f / sums[0];
    const float invr = 1.0f / sums[1];

    float f_t   = sigf(preact[0 * H + j]);
    float i_t   = sigf(preact[1 * H + j]);
    float o_t   = sigf(preact[2 * H + j]);
    float fun_t = sigf(preact[3 * H + j]);
    float rul_t = sigf(preact[4 * H + j]);
    float c_new = tanhf(preact[5 * H + j]);

    float ct = f_t * c_in[j] + i_t * c_new
             + fun_t * tanhf(memfun[j] * invf) + rul_t * tanhf(memrul[j] * invr);
    float ht = o_t * tanhf(ct);

    out[OFF_H + j] = ht;
    out[OFF_C + j] = ct;
    ht_ws[j] = ht;

    out[OFF_FV + (size_t)widx * H + j] = (j < H / 2) ? ct : 0.0f;
    out[OFF_RV + (size_t)widx * H + j] = (j < H / 2) ? 0.0f : ct;
    if (j < FDIM)  out[OFF_FK + (size_t)widx * FDIM + j] = x[j];
    if (j == FDIM) out[OFF_RK + (size_t)widx] = x[FDIM];
}

// ---------------- ha = relu(W_ih @ h_t + b_ih)  (wave per row) ----------------
__global__ __launch_bounds__(256) void k_hidden(
    const float* __restrict__ W_ih, const float* __restrict__ b_ih,
    const float* __restrict__ ht, float* __restrict__ ha)
{
    int gid  = blockIdx.x * blockDim.x + threadIdx.x;
    int row  = gid >> 6;
    int lane = threadIdx.x & 63;
    if (row >= H) return;
    const float4* Wv = (const float4*)(W_ih + (size_t)row * H);
    const float4* hv = (const float4*)ht;
    float acc = 0.0f;
#pragma unroll
    for (int k = 0; k < 8; ++k) {
        float4 w4 = Wv[lane + (k << 6)];
        float4 h4 = hv[lane + (k << 6)];
        acc += w4.x * h4.x + w4.y * h4.y + w4.z * h4.z + w4.w * h4.w;
    }
#pragma unroll
    for (int off = 32; off > 0; off >>= 1) acc += __shfl_down(acc, off);
    if (lane == 0) ha[row] = fmaxf(acc + b_ih[row], 0.0f);
}

// ---------------- heads stage 1: 9 parallel logit GEMVs ----------------
__global__ __launch_bounds__(256) void k_heads1(
    const float* __restrict__ W_actor, const float* __restrict__ b_actor,
    const float* __restrict__ W_critic, const float* __restrict__ b_critic,
    const float* __restrict__ ha, float* __restrict__ logits)
{
    __shared__ float red[4];
    const int o   = blockIdx.x;           // 0..8
    const int tid = threadIdx.x;
    const float* row = (o < 8) ? (W_actor + (size_t)o * H) : W_critic;
    const float4* rv = (const float4*)row;
    const float4* hv = (const float4*)ha;
    float acc = 0.0f;
#pragma unroll
    for (int k = 0; k < 2; ++k) {
        int idx = tid + (k << 8);
        float4 w4 = rv[idx];
        float4 h4 = hv[idx];
        acc += w4.x * h4.x + w4.y * h4.y + w4.z * h4.z + w4.w * h4.w;
    }
#pragma unroll
    for (int off = 32; off > 0; off >>= 1) acc += __shfl_down(acc, off);
    if ((tid & 63) == 0) red[tid >> 6] = acc;
    __syncthreads();
    if (tid == 0)
        logits[o] = red[0] + red[1] + red[2] + red[3] + ((o < 8) ? b_actor[o] : b_critic[0]);
}

// ---------------- heads stage 2: softmax over 8 + critic ----------------
__global__ __launch_bounds__(64) void k_heads2(
    const float* __restrict__ logits, float* __restrict__ out)
{
    if (threadIdx.x == 0) {
        float m = logits[0];
        for (int o = 1; o < 8; ++o) m = fmaxf(m, logits[o]);
        float e[8], s = 0.0f;
        for (int o = 0; o < 8; ++o) { e[o] = expf(logits[o] - m); s += e[o]; }
        for (int o = 0; o < 8; ++o) out[OFF_PI + o] = e[o] / s;
        out[OFF_V] = logits[8];
    }
}

extern "C" void kernel_launch(void* const* d_in, const int* in_sizes, int n_in,
                              void* d_out, int out_size, void* d_ws, size_t ws_size,
                              hipStream_t stream)
{
    const float* x        = (const float*)d_in[0];
    const float* h        = (const float*)d_in[1];
    const float* c        = (const float*)d_in[2];
    const float* W_i2h    = (const float*)d_in[3];
    const float* b_i2h    = (const float*)d_in[4];
    const float* W_h2h    = (const float*)d_in[5];
    const float* b_h2h    = (const float*)d_in[6];
    const float* f_keys   = (const float*)d_in[7];
    const float* f_vals   = (const float*)d_in[8];
    const float* r_keys   = (const float*)d_in[9];
    const float* r_vals   = (const float*)d_in[10];
    const float* W_ih     = (const float*)d_in[11];
    const float* b_ih     = (const float*)d_in[12];
    const float* W_actor  = (const float*)d_in[13];
    const float* b_actor  = (const float*)d_in[14];
    const float* W_critic = (const float*)d_in[15];
    const float* b_critic = (const float*)d_in[16];
    const int*   widx     = (const int*)d_in[17];

    float* out = (float*)d_out;
    float* ws  = (float*)d_ws;

    // ws layout (floats)
    float* preact = ws;                 // 12288
    float* memfun = ws + 12288;         // 2048 ┐
    float* memrul = ws + 14336;         // 2048 ├ zeroed together (4098 floats)
    float* sums   = ws + 16384;         // 2    ┘
    float* ht_ws  = ws + 16388;         // 2048 (16B-aligned)
    float* ha     = ws + 18436;         // 2048 (16B-aligned)
    float* logits = ws + 20484;         // 9

    // 1. zero accumulators (ws is poisoned; atomics accumulate into these)
    k_zero<<<17, 256, 0, stream>>>(memfun, 2 * H + 2);

    // 2. megakernel: vals copy+wsum+sims+keys (blocks 0..799) | preact (800..2335)
    k_mega<<<NBLK_TOTAL, 512, 0, stream>>>(
        f_keys, r_keys, f_vals, r_vals, x,
        W_h2h, W_i2h, b_h2h, b_i2h, h,
        out + OFF_FV, out + OFF_RV, out + OFF_FK, out + OFF_RK,
        memfun, memrul, sums, preact);

    // 3. gates -> c_t, h_t (applies 1/sum normalization); h/c outputs + write_idx rows
    k_combine<<<H / 256, 256, 0, stream>>>(preact, c, memfun, memrul, sums, x, widx, out, ht_ws);

    // 4. heads
    k_hidden<<<H / 4, 256, 0, stream>>>(W_ih, b_ih, ht_ws, ha);
    k_heads1<<<9, 256, 0, stream>>>(W_actor, b_actor, W_critic, b_critic, ha, logits);
    k_heads2<<<1, 64, 0, stream>>>(logits, out);
}

// Round 7
// 415.053 us; speedup vs baseline: 2.4267x; 1.1460x over previous
//
#include <hip/hip_runtime.h>
#include <math.h>

#define H        2048
#define HD       12288      // (NG+1)*H
#define DICT     50000
#define FDIM     6
#define RDIM     1
#define IN_DIM   16
#define EPS_F    1e-8f

// d_out flat offsets (floats), in reference return order
#define OFF_PI   ((size_t)0)
#define OFF_V    ((size_t)8)
#define OFF_H    ((size_t)9)
#define OFF_C    ((size_t)2057)
#define OFF_FK   ((size_t)4105)
#define OFF_FV   ((size_t)304105)    // ≡ 1 (mod 4): row-local float j≡3 (mod 4) is 16B-aligned
#define OFF_RK   ((size_t)102704105)
#define OFF_RV   ((size_t)102754105) // ≡ 1 (mod 4), same phase

// megakernel block ranges
#define R_CHUNK      125                 // vals rows per block
#define NBLK_DICT    (DICT / R_CHUNK)    // 400
#define NBLK_VALS    (2 * NBLK_DICT)     // 800
#define NBLK_PREACT  (HD / 8)            // 1536 (8 rows per 512-thread block)
#define NBLK_TOTAL   (NBLK_VALS + NBLK_PREACT)

typedef float f4v  __attribute__((ext_vector_type(4)));  // 16B-aligned vector
typedef f4v  f4vu  __attribute__((aligned(4)));          // 4B-aligned vector: one dwordx4, HW-unaligned

__device__ __forceinline__ float sigf(float v) { return 1.0f / (1.0f + expf(-v)); }

// ---------------- zero scratch accumulators ----------------
__global__ void k_zero(float* __restrict__ p, int n) {
    int i = blockIdx.x * 256 + threadIdx.x;
    if (i < n) p[i] = 0.0f;
}

// ---------------- megakernel: vals copy+wsum+sims (blocks 0..799) | preact (800..2335) ----
__global__ __launch_bounds__(512) void k_mega(
    const float* __restrict__ f_keys, const float* __restrict__ r_keys,
    const float* __restrict__ f_vals, const float* __restrict__ r_vals,
    const float* __restrict__ x,
    const float* __restrict__ W_h2h, const float* __restrict__ W_i2h,
    const float* __restrict__ b_h2h, const float* __restrict__ b_i2h,
    const float* __restrict__ h,
    float* __restrict__ out_fv, float* __restrict__ out_rv,
    float* __restrict__ out_fk, float* __restrict__ out_rk,
    float* __restrict__ memfun, float* __restrict__ memrul,
    float* __restrict__ sums, float* __restrict__ preact)
{
    const int b   = blockIdx.x;
    const int tid = threadIdx.x;

    if (b >= NBLK_VALS) {
        // ---- preact: wave per row, 8 rows per block ----
        const int row  = (b - NBLK_VALS) * 8 + (tid >> 6);
        const int lane = tid & 63;
        const float4* Wv = (const float4*)(W_h2h + (size_t)row * H);
        const float4* hv = (const float4*)h;
        float acc = 0.0f;
#pragma unroll
        for (int k = 0; k < 8; ++k) {
            float4 w4 = Wv[lane + (k << 6)];
            float4 h4 = hv[lane + (k << 6)];
            acc += w4.x * h4.x + w4.y * h4.y + w4.z * h4.z + w4.w * h4.w;
        }
        if (lane < IN_DIM) acc += W_i2h[(size_t)row * IN_DIM + lane] * x[lane];
#pragma unroll
        for (int off = 32; off > 0; off >>= 1) acc += __shfl_down(acc, off);
        if (lane == 0) preact[row] = acc + b_h2h[row] + b_i2h[row];
        return;
    }

    // ---- vals blocks ----
    __shared__ float wl[R_CHUNK];
    const int  dict = (b >= NBLK_DICT) ? 1 : 0;
    const int  row0 = (dict ? b - NBLK_DICT : b) * R_CHUNK;

    const float* vals = dict ? r_vals : f_vals;
    float*       outv = dict ? out_rv : out_fv;   // base ≡ 1 (mod 4 floats)
    float*       mem  = dict ? memrul : memfun;

    // fused keys output copy + exp-sims (softmax max-shift unneeded: |sim|<=1)
    if (!dict) {
        for (int i = tid; i < R_CHUNK * FDIM; i += 512)
            out_fk[(size_t)row0 * FDIM + i] = f_keys[(size_t)row0 * FDIM + i];
    } else if (tid < R_CHUNK) {
        out_rk[row0 + tid] = r_keys[row0 + tid];
    }
    if (tid < R_CHUNK) {
        const int row = row0 + tid;
        float e;
        if (!dict) {
            float qn[FDIM]; float qs = 0.0f;
#pragma unroll
            for (int d = 0; d < FDIM; ++d) { float q = x[d]; qn[d] = q; qs += q * q; }
            const float qi = 1.0f / (sqrtf(qs) + EPS_F);
            float ks = 0.0f, dot = 0.0f;
#pragma unroll
            for (int d = 0; d < FDIM; ++d) {
                float kv = f_keys[(size_t)row * FDIM + d];
                ks += kv * kv; dot += kv * qn[d];
            }
            e = expf((dot * qi) / (sqrtf(ks) + EPS_F));
        } else {
            float q  = x[FDIM];
            float kv = r_keys[row];
            e = expf((kv * (q / (fabsf(q) + EPS_F))) / (fabsf(kv) + EPS_F));
        }
        wl[tid] = e;
    }
    __syncthreads();
    if (tid == 0) {
        float s = 0.0f;
        for (int i = 0; i < R_CHUNK; ++i) s += wl[i];
        atomicAdd(&sums[dict], s);
    }

    // ---- streaming copy + weighted sum ----
    // tid<511: owns row-local floats j0..j0+3, j0=4t+3 (16B-aligned in out).
    //   One unaligned dwordx4 load + one aligned dwordx4 store per row.
    // tid==511: edge floats {0,1,2,2047} per row.
    // Unroll 4 rows per barrier: block issues a contiguous 32KB read burst,
    // then a contiguous 32KB write burst, all 8 waves in lockstep.
    float a0 = 0.f, a1 = 0.f, a2 = 0.f, a3 = 0.f;
    const float* src = vals + (size_t)row0 * 2048;
    float*       dst = outv + (size_t)row0 * 2048;
    const int j0 = 4 * tid + 3;

    int i = 0;
    for (; i + 4 <= R_CHUNK; i += 4) {
        if (tid < 511) {
            const float* s0 = src + (size_t)i * 2048 + j0;
            f4vu v0 = *(const f4vu*)(s0);
            f4vu v1 = *(const f4vu*)(s0 + 2048);
            f4vu v2 = *(const f4vu*)(s0 + 4096);
            f4vu v3 = *(const f4vu*)(s0 + 6144);
            const float w0 = wl[i], w1 = wl[i + 1], w2 = wl[i + 2], w3 = wl[i + 3];
            a0 += w0 * v0.x + w1 * v1.x + w2 * v2.x + w3 * v3.x;
            a1 += w0 * v0.y + w1 * v1.y + w2 * v2.y + w3 * v3.y;
            a2 += w0 * v0.z + w1 * v1.z + w2 * v2.z + w3 * v3.z;
            a3 += w0 * v0.w + w1 * v1.w + w2 * v2.w + w3 * v3.w;
            float* d0 = dst + (size_t)i * 2048 + j0;
            *(f4v*)(d0)        = v0;
            *(f4v*)(d0 + 2048) = v1;
            *(f4v*)(d0 + 4096) = v2;
            *(f4v*)(d0 + 6144) = v3;
        } else {
#pragma unroll
            for (int r = 0; r < 4; ++r) {
                const float* vr = src + (size_t)(i + r) * 2048;
                float*       dr = dst + (size_t)(i + r) * 2048;
                float v0 = vr[0], v1 = vr[1], v2 = vr[2], v3 = vr[2047];
                const float w = wl[i + r];
                a0 += w * v0; a1 += w * v1; a2 += w * v2; a3 += w * v3;
                dr[0] = v0; dr[1] = v1; dr[2] = v2; dr[2047] = v3;
            }
        }
        __syncthreads();
    }
    // tail row (125 = 31*4 + 1)
    for (; i < R_CHUNK; ++i) {
        if (tid < 511) {
            const float* s0 = src + (size_t)i * 2048 + j0;
            f4vu v = *(const f4vu*)(s0);
            const float w = wl[i];
            a0 += w * v.x; a1 += w * v.y; a2 += w * v.z; a3 += w * v.w;
            *(f4v*)(dst + (size_t)i * 2048 + j0) = v;
        } else {
            const float* vr = src + (size_t)i * 2048;
            float*       dr = dst + (size_t)i * 2048;
            float v0 = vr[0], v1 = vr[1], v2 = vr[2], v3 = vr[2047];
            const float w = wl[i];
            a0 += w * v0; a1 += w * v1; a2 += w * v2; a3 += w * v3;
            dr[0] = v0; dr[1] = v1; dr[2] = v2; dr[2047] = v3;
        }
    }

    if (tid < 511) {
        atomicAdd(&mem[j0 + 0], a0);
        atomicAdd(&mem[j0 + 1], a1);
        atomicAdd(&mem[j0 + 2], a2);
        atomicAdd(&mem[j0 + 3], a3);
    } else {
        atomicAdd(&mem[0],    a0);
        atomicAdd(&mem[1],    a1);
        atomicAdd(&mem[2],    a2);
        atomicAdd(&mem[2047], a3);
    }
}

// ---------------- gates -> c_t, h_t; write h/c outputs + write_idx rows ----------------
__global__ __launch_bounds__(256) void k_combine(
    const float* __restrict__ preact, const float* __restrict__ c_in,
    const float* __restrict__ memfun, const float* __restrict__ memrul,
    const float* __restrict__ sums,
    const float* __restrict__ x, const int* __restrict__ widx_p,
    float* __restrict__ out, float* __restrict__ ht_ws)
{
    const int j = blockIdx.x * 256 + threadIdx.x;
    if (j >= H) return;
    const int widx = *widx_p;
    const float invf = 1.0f / sums[0];
    const float invr = 1.0f / sums[1];

    float f_t   = sigf(preact[0 * H + j]);
    float i_t   = sigf(preact[1 * H + j]);
    float o_t   = sigf(preact[2 * H + j]);
    float fun_t = sigf(preact[3 * H + j]);
    float rul_t = sigf(preact[4 * H + j]);
    float c_new = tanhf(preact[5 * H + j]);

    float ct = f_t * c_in[j] + i_t * c_new
             + fun_t * tanhf(memfun[j] * invf) + rul_t * tanhf(memrul[j] * invr);
    float ht = o_t * tanhf(ct);

    out[OFF_H + j] = ht;
    out[OFF_C + j] = ct;
    ht_ws[j] = ht;

    out[OFF_FV + (size_t)widx * H + j] = (j < H / 2) ? ct : 0.0f;
    out[OFF_RV + (size_t)widx * H + j] = (j < H / 2) ? 0.0f : ct;
    if (j < FDIM)  out[OFF_FK + (size_t)widx * FDIM + j] = x[j];
    if (j == FDIM) out[OFF_RK + (size_t)widx] = x[FDIM];
}

// ---------------- ha = relu(W_ih @ h_t + b_ih)  (wave per row) ----------------
__global__ __launch_bounds__(256) void k_hidden(
    const float* __restrict__ W_ih, const float* __restrict__ b_ih,
    const float* __restrict__ ht, float* __restrict__ ha)
{
    int gid  = blockIdx.x * blockDim.x + threadIdx.x;
    int row  = gid >> 6;
    int lane = threadIdx.x & 63;
    if (row >= H) return;
    const float4* Wv = (const float4*)(W_ih + (size_t)row * H);
    const float4* hv = (const float4*)ht;
    float acc = 0.0f;
#pragma unroll
    for (int k = 0; k < 8; ++k) {
        float4 w4 = Wv[lane + (k << 6)];
        float4 h4 = hv[lane + (k << 6)];
        acc += w4.x * h4.x + w4.y * h4.y + w4.z * h4.z + w4.w * h4.w;
    }
#pragma unroll
    for (int off = 32; off > 0; off >>= 1) acc += __shfl_down(acc, off);
    if (lane == 0) ha[row] = fmaxf(acc + b_ih[row], 0.0f);
}

// ---------------- heads stage 1: 9 parallel logit GEMVs ----------------
__global__ __launch_bounds__(256) void k_heads1(
    const float* __restrict__ W_actor, const float* __restrict__ b_actor,
    const float* __restrict__ W_critic, const float* __restrict__ b_critic,
    const float* __restrict__ ha, float* __restrict__ logits)
{
    __shared__ float red[4];
    const int o   = blockIdx.x;           // 0..8
    const int tid = threadIdx.x;
    const float* row = (o < 8) ? (W_actor + (size_t)o * H) : W_critic;
    const float4* rv = (const float4*)row;
    const float4* hv = (const float4*)ha;
    float acc = 0.0f;
#pragma unroll
    for (int k = 0; k < 2; ++k) {
        int idx = tid + (k << 8);
        float4 w4 = rv[idx];
        float4 h4 = hv[idx];
        acc += w4.x * h4.x + w4.y * h4.y + w4.z * h4.z + w4.w * h4.w;
    }
#pragma unroll
    for (int off = 32; off > 0; off >>= 1) acc += __shfl_down(acc, off);
    if ((tid & 63) == 0) red[tid >> 6] = acc;
    __syncthreads();
    if (tid == 0)
        logits[o] = red[0] + red[1] + red[2] + red[3] + ((o < 8) ? b_actor[o] : b_critic[0]);
}

// ---------------- heads stage 2: softmax over 8 + critic ----------------
__global__ __launch_bounds__(64) void k_heads2(
    const float* __restrict__ logits, float* __restrict__ out)
{
    if (threadIdx.x == 0) {
        float m = logits[0];
        for (int o = 1; o < 8; ++o) m = fmaxf(m, logits[o]);
        float e[8], s = 0.0f;
        for (int o = 0; o < 8; ++o) { e[o] = expf(logits[o] - m); s += e[o]; }
        for (int o = 0; o < 8; ++o) out[OFF_PI + o] = e[o] / s;
        out[OFF_V] = logits[8];
    }
}

extern "C" void kernel_launch(void* const* d_in, const int* in_sizes, int n_in,
                              void* d_out, int out_size, void* d_ws, size_t ws_size,
                              hipStream_t stream)
{
    const float* x        = (const float*)d_in[0];
    const float* h        = (const float*)d_in[1];
    const float* c        = (const float*)d_in[2];
    const float* W_i2h    = (const float*)d_in[3];
    const float* b_i2h    = (const float*)d_in[4];
    const float* W_h2h    = (const float*)d_in[5];
    const float* b_h2h    = (const float*)d_in[6];
    const float* f_keys   = (const float*)d_in[7];
    const float* f_vals   = (const float*)d_in[8];
    const float* r_keys   = (const float*)d_in[9];
    const float* r_vals   = (const float*)d_in[10];
    const float* W_ih     = (const float*)d_in[11];
    const float* b_ih     = (const float*)d_in[12];
    const float* W_actor  = (const float*)d_in[13];
    const float* b_actor  = (const float*)d_in[14];
    const float* W_critic = (const float*)d_in[15];
    const float* b_critic = (const float*)d_in[16];
    const int*   widx     = (const int*)d_in[17];

    float* out = (float*)d_out;
    float* ws  = (float*)d_ws;

    // ws layout (floats)
    float* preact = ws;                 // 12288
    float* memfun = ws + 12288;         // 2048 ┐
    float* memrul = ws + 14336;         // 2048 ├ zeroed together (4098 floats)
    float* sums   = ws + 16384;         // 2    ┘
    float* ht_ws  = ws + 16388;         // 2048 (16B-aligned)
    float* ha     = ws + 18436;         // 2048 (16B-aligned)
    float* logits = ws + 20484;         // 9

    // 1. zero accumulators (ws is poisoned; atomics accumulate into these)
    k_zero<<<17, 256, 0, stream>>>(memfun, 2 * H + 2);

    // 2. megakernel: vals copy+wsum+sims+keys (blocks 0..799) | preact (800..2335)
    k_mega<<<NBLK_TOTAL, 512, 0, stream>>>(
        f_keys, r_keys, f_vals, r_vals, x,
        W_h2h, W_i2h, b_h2h, b_i2h, h,
        out + OFF_FV, out + OFF_RV, out + OFF_FK, out + OFF_RK,
        memfun, memrul, sums, preact);

    // 3. gates -> c_t, h_t (applies 1/sum normalization); h/c outputs + write_idx rows
    k_combine<<<H / 256, 256, 0, stream>>>(preact, c, memfun, memrul, sums, x, widx, out, ht_ws);

    // 4. heads
    k_hidden<<<H / 4, 256, 0, stream>>>(W_ih, b_ih, ht_ws, ha);
    k_heads1<<<9, 256, 0, stream>>>(W_actor, b_actor, W_critic, b_critic, ha, logits);
    k_heads2<<<1, 64, 0, stream>>>(logits, out);
}

// Round 8
// 400.689 us; speedup vs baseline: 2.5137x; 1.0358x over previous
//
#include <hip/hip_runtime.h>
#include <math.h>

#define H        2048
#define HD       12288      // (NG+1)*H
#define DICT     50000
#define FDIM     6
#define RDIM     1
#define IN_DIM   16
#define EPS_F    1e-8f

// d_out flat offsets (floats), in reference return order
#define OFF_PI   ((size_t)0)
#define OFF_V    ((size_t)8)
#define OFF_H    ((size_t)9)
#define OFF_C    ((size_t)2057)
#define OFF_FK   ((size_t)4105)
#define OFF_FV   ((size_t)304105)    // ≡ 1 (mod 4): row-local float j≡3 (mod 4) is 16B-aligned
#define OFF_RK   ((size_t)102704105)
#define OFF_RV   ((size_t)102754105) // ≡ 1 (mod 4), same phase

// megakernel block ranges
#define R_CHUNK      125                 // vals rows per block
#define NBLK_DICT    (DICT / R_CHUNK)    // 400
#define NBLK_VALS    (2 * NBLK_DICT)     // 800
#define NBLK_PREACT  (HD / 8)            // 1536 (8 rows per 512-thread block)
#define NBLK_TOTAL   (NBLK_VALS + NBLK_PREACT)

typedef float f4v __attribute__((ext_vector_type(4)));

__device__ __forceinline__ float sigf(float v) { return 1.0f / (1.0f + expf(-v)); }

// ---------------- zero scratch accumulators ----------------
__global__ void k_zero(float* __restrict__ p, int n) {
    int i = blockIdx.x * 256 + threadIdx.x;
    if (i < n) p[i] = 0.0f;
}

// ---------------- megakernel: vals copy+wsum+sims (blocks 0..799) | preact (800..2335) ----
__global__ __launch_bounds__(512) void k_mega(
    const float* __restrict__ f_keys, const float* __restrict__ r_keys,
    const float* __restrict__ f_vals, const float* __restrict__ r_vals,
    const float* __restrict__ x,
    const float* __restrict__ W_h2h, const float* __restrict__ W_i2h,
    const float* __restrict__ b_h2h, const float* __restrict__ b_i2h,
    const float* __restrict__ h,
    float* __restrict__ out_fv, float* __restrict__ out_rv,
    float* __restrict__ out_fk, float* __restrict__ out_rk,
    float* __restrict__ memfun, float* __restrict__ memrul,
    float* __restrict__ sums, float* __restrict__ preact)
{
    const int b   = blockIdx.x;
    const int tid = threadIdx.x;

    if (b >= NBLK_VALS) {
        // ---- preact: wave per row, 8 rows per block ----
        const int row  = (b - NBLK_VALS) * 8 + (tid >> 6);
        const int lane = tid & 63;
        const float4* Wv = (const float4*)(W_h2h + (size_t)row * H);
        const float4* hv = (const float4*)h;
        float acc = 0.0f;
#pragma unroll
        for (int k = 0; k < 8; ++k) {
            float4 w4 = Wv[lane + (k << 6)];
            float4 h4 = hv[lane + (k << 6)];
            acc += w4.x * h4.x + w4.y * h4.y + w4.z * h4.z + w4.w * h4.w;
        }
        if (lane < IN_DIM) acc += W_i2h[(size_t)row * IN_DIM + lane] * x[lane];
#pragma unroll
        for (int off = 32; off > 0; off >>= 1) acc += __shfl_down(acc, off);
        if (lane == 0) preact[row] = acc + b_h2h[row] + b_i2h[row];
        return;
    }

    // ---- vals blocks ----
    __shared__ float wl[R_CHUNK];
    const int  dict = (b >= NBLK_DICT) ? 1 : 0;
    const int  row0 = (dict ? b - NBLK_DICT : b) * R_CHUNK;

    const float* vals = dict ? r_vals : f_vals;
    float*       outv = dict ? out_rv : out_fv;   // base ≡ 1 (mod 4 floats)
    float*       mem  = dict ? memrul : memfun;

    // fused keys output copy + exp-sims (softmax max-shift unneeded: |sim|<=1)
    if (!dict) {
        for (int i = tid; i < R_CHUNK * FDIM; i += 512)
            out_fk[(size_t)row0 * FDIM + i] = f_keys[(size_t)row0 * FDIM + i];
    } else if (tid < R_CHUNK) {
        out_rk[row0 + tid] = r_keys[row0 + tid];
    }
    if (tid < R_CHUNK) {
        const int row = row0 + tid;
        float e;
        if (!dict) {
            float qn[FDIM]; float qs = 0.0f;
#pragma unroll
            for (int d = 0; d < FDIM; ++d) { float q = x[d]; qn[d] = q; qs += q * q; }
            const float qi = 1.0f / (sqrtf(qs) + EPS_F);
            float ks = 0.0f, dot = 0.0f;
#pragma unroll
            for (int d = 0; d < FDIM; ++d) {
                float kv = f_keys[(size_t)row * FDIM + d];
                ks += kv * kv; dot += kv * qn[d];
            }
            e = expf((dot * qi) / (sqrtf(ks) + EPS_F));
        } else {
            float q  = x[FDIM];
            float kv = r_keys[row];
            e = expf((kv * (q / (fabsf(q) + EPS_F))) / (fabsf(kv) + EPS_F));
        }
        wl[tid] = e;
    }
    __syncthreads();
    if (tid == 0) {
        float s = 0.0f;
        for (int i = 0; i < R_CHUNK; ++i) s += wl[i];
        atomicAdd(&sums[dict], s);
    }

    // ---- streaming copy + weighted sum, BOTH global streams aligned ----
    // Load: thread t loads ALIGNED src quad j=4t..4t+3 (one dwordx4, 16B-aligned).
    // wsum: thread t owns aligned columns 4t..4t+3 (uniform atomics).
    // Store: thread t<511 stores ALIGNED out quad at 4t+3 = (v.w, next.x/y/z),
    //        neighbor via __shfl_down(.,1); lane 63 reloads neighbor quad (L1-hot).
    //        tid 0 stores edge floats 0,1,2; tid 511 stores edge float 2047.
    // Unroll 4 rows per barrier: contiguous 32KB read burst then write burst.
    const float* src = vals + (size_t)row0 * 2048;
    float*       dst = outv + (size_t)row0 * 2048;
    const int lane = tid & 63;
    const int j0   = 4 * tid;
    float a0 = 0.f, a1 = 0.f, a2 = 0.f, a3 = 0.f;

    int i = 0;
    for (; i + 4 <= R_CHUNK; i += 4) {
        f4v v0 = *(const f4v*)(src + (size_t)(i    ) * 2048 + j0);
        f4v v1 = *(const f4v*)(src + (size_t)(i + 1) * 2048 + j0);
        f4v v2 = *(const f4v*)(src + (size_t)(i + 2) * 2048 + j0);
        f4v v3 = *(const f4v*)(src + (size_t)(i + 3) * 2048 + j0);
        const float w0 = wl[i], w1 = wl[i + 1], w2 = wl[i + 2], w3 = wl[i + 3];
        a0 += w0 * v0.x + w1 * v1.x + w2 * v2.x + w3 * v3.x;
        a1 += w0 * v0.y + w1 * v1.y + w2 * v2.y + w3 * v3.y;
        a2 += w0 * v0.z + w1 * v1.z + w2 * v2.z + w3 * v3.z;
        a3 += w0 * v0.w + w1 * v1.w + w2 * v2.w + w3 * v3.w;
#pragma unroll
        for (int r = 0; r < 4; ++r) {
            f4v v = (r == 0) ? v0 : (r == 1) ? v1 : (r == 2) ? v2 : v3;
            float nx = __shfl_down(v.x, 1);
            float ny = __shfl_down(v.y, 1);
            float nz = __shfl_down(v.z, 1);
            const float* srow = src + (size_t)(i + r) * 2048;
            float*       drow = dst + (size_t)(i + r) * 2048;
            if (lane == 63 && tid != 511) {
                const float* nq = srow + j0 + 4;
                nx = nq[0]; ny = nq[1]; nz = nq[2];
            }
            if (tid < 511) {
                f4v s; s.x = v.w; s.y = nx; s.z = ny; s.w = nz;
                *(f4v*)(drow + j0 + 3) = s;
            } else {
                drow[2047] = v.w;
            }
            if (tid == 0) { drow[0] = v.x; drow[1] = v.y; drow[2] = v.z; }
        }
        __syncthreads();
    }
    // tail row (125 = 31*4 + 1)
    for (; i < R_CHUNK; ++i) {
        f4v v = *(const f4v*)(src + (size_t)i * 2048 + j0);
        const float w = wl[i];
        a0 += w * v.x; a1 += w * v.y; a2 += w * v.z; a3 += w * v.w;
        float nx = __shfl_down(v.x, 1);
        float ny = __shfl_down(v.y, 1);
        float nz = __shfl_down(v.z, 1);
        const float* srow = src + (size_t)i * 2048;
        float*       drow = dst + (size_t)i * 2048;
        if (lane == 63 && tid != 511) {
            const float* nq = srow + j0 + 4;
            nx = nq[0]; ny = nq[1]; nz = nq[2];
        }
        if (tid < 511) {
            f4v s; s.x = v.w; s.y = nx; s.z = ny; s.w = nz;
            *(f4v*)(drow + j0 + 3) = s;
        } else {
            drow[2047] = v.w;
        }
        if (tid == 0) { drow[0] = v.x; drow[1] = v.y; drow[2] = v.z; }
    }

    atomicAdd(&mem[j0 + 0], a0);
    atomicAdd(&mem[j0 + 1], a1);
    atomicAdd(&mem[j0 + 2], a2);
    atomicAdd(&mem[j0 + 3], a3);
}

// ---------------- gates -> c_t, h_t; write h/c outputs + write_idx rows ----------------
__global__ __launch_bounds__(256) void k_combine(
    const float* __restrict__ preact, const float* __restrict__ c_in,
    const float* __restrict__ memfun, const float* __restrict__ memrul,
    const float* __restrict__ sums,
    const float* __restrict__ x, const int* __restrict__ widx_p,
    float* __restrict__ out, float* __restrict__ ht_ws)
{
    const int j = blockIdx.x * 256 + threadIdx.x;
    if (j >= H) return;
    const int widx = *widx_p;
    const float invf = 1.0f / sums[0];
    const float invr = 1.0f / sums[1];

    float f_t   = sigf(preact[0 * H + j]);
    float i_t   = sigf(preact[1 * H + j]);
    float o_t   = sigf(preact[2 * H + j]);
    float fun_t = sigf(preact[3 * H + j]);
    float rul_t = sigf(preact[4 * H + j]);
    float c_new = tanhf(preact[5 * H + j]);

    float ct = f_t * c_in[j] + i_t * c_new
             + fun_t * tanhf(memfun[j] * invf) + rul_t * tanhf(memrul[j] * invr);
    float ht = o_t * tanhf(ct);

    out[OFF_H + j] = ht;
    out[OFF_C + j] = ct;
    ht_ws[j] = ht;

    out[OFF_FV + (size_t)widx * H + j] = (j < H / 2) ? ct : 0.0f;
    out[OFF_RV + (size_t)widx * H + j] = (j < H / 2) ? 0.0f : ct;
    if (j < FDIM)  out[OFF_FK + (size_t)widx * FDIM + j] = x[j];
    if (j == FDIM) out[OFF_RK + (size_t)widx] = x[FDIM];
}

// ---------------- ha = relu(W_ih @ h_t + b_ih)  (wave per row) ----------------
__global__ __launch_bounds__(256) void k_hidden(
    const float* __restrict__ W_ih, const float* __restrict__ b_ih,
    const float* __restrict__ ht, float* __restrict__ ha)
{
    int gid  = blockIdx.x * blockDim.x + threadIdx.x;
    int row  = gid >> 6;
    int lane = threadIdx.x & 63;
    if (row >= H) return;
    const float4* Wv = (const float4*)(W_ih + (size_t)row * H);
    const float4* hv = (const float4*)ht;
    float acc = 0.0f;
#pragma unroll
    for (int k = 0; k < 8; ++k) {
        float4 w4 = Wv[lane + (k << 6)];
        float4 h4 = hv[lane + (k << 6)];
        acc += w4.x * h4.x + w4.y * h4.y + w4.z * h4.z + w4.w * h4.w;
    }
#pragma unroll
    for (int off = 32; off > 0; off >>= 1) acc += __shfl_down(acc, off);
    if (lane == 0) ha[row] = fmaxf(acc + b_ih[row], 0.0f);
}

// ---------------- heads stage 1: 9 parallel logit GEMVs ----------------
__global__ __launch_bounds__(256) void k_heads1(
    const float* __restrict__ W_actor, const float* __restrict__ b_actor,
    const float* __restrict__ W_critic, const float* __restrict__ b_critic,
    const float* __restrict__ ha, float* __restrict__ logits)
{
    __shared__ float red[4];
    const int o   = blockIdx.x;           // 0..8
    const int tid = threadIdx.x;
    const float* row = (o < 8) ? (W_actor + (size_t)o * H) : W_critic;
    const float4* rv = (const float4*)row;
    const float4* hv = (const float4*)ha;
    float acc = 0.0f;
#pragma unroll
    for (int k = 0; k < 2; ++k) {
        int idx = tid + (k << 8);
        float4 w4 = rv[idx];
        float4 h4 = hv[idx];
        acc += w4.x * h4.x + w4.y * h4.y + w4.z * h4.z + w4.w * h4.w;
    }
#pragma unroll
    for (int off = 32; off > 0; off >>= 1) acc += __shfl_down(acc, off);
    if ((tid & 63) == 0) red[tid >> 6] = acc;
    __syncthreads();
    if (tid == 0)
        logits[o] = red[0] + red[1] + red[2] + red[3] + ((o < 8) ? b_actor[o] : b_critic[0]);
}

// ---------------- heads stage 2: softmax over 8 + critic ----------------
__global__ __launch_bounds__(64) void k_heads2(
    const float* __restrict__ logits, float* __restrict__ out)
{
    if (threadIdx.x == 0) {
        float m = logits[0];
        for (int o = 1; o < 8; ++o) m = fmaxf(m, logits[o]);
        float e[8], s = 0.0f;
        for (int o = 0; o < 8; ++o) { e[o] = expf(logits[o] - m); s += e[o]; }
        for (int o = 0; o < 8; ++o) out[OFF_PI + o] = e[o] / s;
        out[OFF_V] = logits[8];
    }
}

extern "C" void kernel_launch(void* const* d_in, const int* in_sizes, int n_in,
                              void* d_out, int out_size, void* d_ws, size_t ws_size,
                              hipStream_t stream)
{
    const float* x        = (const float*)d_in[0];
    const float* h        = (const float*)d_in[1];
    const float* c        = (const float*)d_in[2];
    const float* W_i2h    = (const float*)d_in[3];
    const float* b_i2h    = (const float*)d_in[4];
    const float* W_h2h    = (const float*)d_in[5];
    const float* b_h2h    = (const float*)d_in[6];
    const float* f_keys   = (const float*)d_in[7];
    const float* f_vals   = (const float*)d_in[8];
    const float* r_keys   = (const float*)d_in[9];
    const float* r_vals   = (const float*)d_in[10];
    const float* W_ih     = (const float*)d_in[11];
    const float* b_ih     = (const float*)d_in[12];
    const float* W_actor  = (const float*)d_in[13];
    const float* b_actor  = (const float*)d_in[14];
    const float* W_critic = (const float*)d_in[15];
    const float* b_critic = (const float*)d_in[16];
    const int*   widx     = (const int*)d_in[17];

    float* out = (float*)d_out;
    float* ws  = (float*)d_ws;

    // ws layout (floats)
    float* preact = ws;                 // 12288
    float* memfun = ws + 12288;         // 2048 ┐
    float* memrul = ws + 14336;         // 2048 ├ zeroed together (4098 floats)
    float* sums   = ws + 16384;         // 2    ┘
    float* ht_ws  = ws + 16388;         // 2048 (16B-aligned)
    float* ha     = ws + 18436;         // 2048 (16B-aligned)
    float* logits = ws + 20484;         // 9

    // 1. zero accumulators (ws is poisoned; atomics accumulate into these)
    k_zero<<<17, 256, 0, stream>>>(memfun, 2 * H + 2);

    // 2. megakernel: vals copy+wsum+sims+keys (blocks 0..799) | preact (800..2335)
    k_mega<<<NBLK_TOTAL, 512, 0, stream>>>(
        f_keys, r_keys, f_vals, r_vals, x,
        W_h2h, W_i2h, b_h2h, b_i2h, h,
        out + OFF_FV, out + OFF_RV, out + OFF_FK, out + OFF_RK,
        memfun, memrul, sums, preact);

    // 3. gates -> c_t, h_t (applies 1/sum normalization); h/c outputs + write_idx rows
    k_combine<<<H / 256, 256, 0, stream>>>(preact, c, memfun, memrul, sums, x, widx, out, ht_ws);

    // 4. heads
    k_hidden<<<H / 4, 256, 0, stream>>>(W_ih, b_ih, ht_ws, ha);
    k_heads1<<<9, 256, 0, stream>>>(W_actor, b_actor, W_critic, b_critic, ha, logits);
    k_heads2<<<1, 64, 0, stream>>>(logits, out);
}